// Round 2
// baseline (247.266 us; speedup 1.0000x reference)
//
#include <hip/hip_runtime.h>
#include <hip/hip_bf16.h>

// out[1,512] = sum_rows(relu(concat(v0,v1) @ W.T + b))
// bf16 MFMA 16x16x32, f32 accum. W pre-converted to bf16 (L2-resident).
// A: reg-staged depth-2 -> LDS (XOR-swizzled). B: global_load_lds width-16,
// source pre-swizzled so linear LDS write lands swizzled (rule 21).

typedef __bf16 bf16x8 __attribute__((ext_vector_type(8)));
typedef float  f32x4  __attribute__((ext_vector_type(4)));
typedef unsigned short u16x4 __attribute__((ext_vector_type(4)));

#define BM 128
#define BN 128
#define BK 32
#define NK 16          // 512 / 32
#define SLOTS 128
#define NCB 4

static __device__ __forceinline__ int swz(int r) { return (r & 3) ^ ((r >> 2) & 3); }
static __device__ __forceinline__ unsigned short f2bf(float f) {
    return __builtin_bit_cast(unsigned short, (__bf16)f);
}
static __device__ __forceinline__ bf16x8 pack8(float4 a, float4 b) {
    bf16x8 o;
    o[0] = (__bf16)a.x; o[1] = (__bf16)a.y; o[2] = (__bf16)a.z; o[3] = (__bf16)a.w;
    o[4] = (__bf16)b.x; o[5] = (__bf16)b.y; o[6] = (__bf16)b.z; o[7] = (__bf16)b.w;
    return o;
}

#define GLDS16(G, L) __builtin_amdgcn_global_load_lds(                       \
    (const __attribute__((address_space(1))) void*)(G),                     \
    (__attribute__((address_space(3))) void*)(L), 16, 0, 0)

__global__ void conv_w_bf16(const float* __restrict__ W, unsigned short* __restrict__ Wb) {
    int idx = (blockIdx.x * blockDim.x + threadIdx.x) * 4;   // 512*512 elems, exact
    float4 f = *(const float4*)(W + idx);
    u16x4 p;
    p[0] = f2bf(f.x); p[1] = f2bf(f.y); p[2] = f2bf(f.z); p[3] = f2bf(f.w);
    *(u16x4*)(Wb + idx) = p;
}

template<bool WBF16>
__global__ __launch_bounds__(256) void fused_gemm_pool(
    const float* __restrict__ v0, const float* __restrict__ v1,
    const float* __restrict__ Wf, const unsigned short* __restrict__ Wb,
    const float* __restrict__ b,
    float* __restrict__ partial, int N, int numRB)
{
    __shared__ unsigned short As[2][BM * BK];   // 2 x 8 KB, bf16, XOR-swizzled chunks
    __shared__ unsigned short Bs[2][BN * BK];   // 2 x 8 KB
    __shared__ float ldsPart[4][64];

    int bid   = blockIdx.x;
    int group = bid >> 5;          // 8 XCDs x 4 col-blocks per group
    int xcd   = bid & 7;
    int cb    = (bid >> 3) & 3;
    int slot  = group * 8 + xcd;   // 0..127

    int tid = threadIdx.x, wid = tid >> 6, lane = tid & 63;
    int wr = wid >> 1, wc = wid & 1, l15 = lane & 15, l4 = lane >> 4;

    // ---- per-thread constant offsets (hoisted out of all loops) ----
    int rowA[2], offAg[2], offAw[2], offBg[2], offBw[2], offBgl[2];
    #pragma unroll
    for (int i = 0; i < 2; ++i) {
        int m = tid + i * 256;          // 16B bf16 chunk index 0..511
        int r = m >> 2, c = m & 3;
        rowA[i]  = r;
        offAg[i] = r * 256 + c * 8;                 // f32 elements (+k0)
        offAw[i] = r * BK + ((c ^ swz(r)) * 8);     // ushort offset in As
        offBg[i] = (cb * 128 + r) * 512 + c * 8;    // f32 W elements (+k0), fallback
        offBw[i] = offAw[i];
        int mu = (wid + i * 4) * 64 + lane;         // glds: chunk this lane feeds
        int br = mu >> 2, bc = mu & 3;
        offBgl[i] = (cb * 128 + br) * 512 + ((bc ^ swz(br)) * 8);  // bf16 elems (+kt*32)
    }
    int offAf[4], offBf[4];
    #pragma unroll
    for (int f = 0; f < 4; ++f) {
        int r = wr * 64 + f * 16 + l15;
        offAf[f] = r * BK + ((l4 ^ swz(r)) * 8);
        int cc = wc * 64 + f * 16 + l15;
        offBf[f] = cc * BK + ((l4 ^ swz(cc)) * 8);
    }

    float bv[4];
    #pragma unroll
    for (int nf = 0; nf < 4; ++nf) bv[nf] = b[cb * 128 + wc * 64 + nf * 16 + l15];

    float csum[4] = {0.f, 0.f, 0.f, 0.f};
    float4 rA[2][4];       // depth-2 raw A (f32) staging
    float4 rB[2][4];       // fallback only (W f32)

    for (int rbk = slot; rbk < numRB; rbk += SLOTS) {
        int rowBase = rbk * BM;

        f32x4 acc[4][4];
        #pragma unroll
        for (int mf = 0; mf < 4; ++mf)
            #pragma unroll
            for (int nf = 0; nf < 4; ++nf)
                acc[mf][nf] = (f32x4){0.f, 0.f, 0.f, 0.f};

        auto loadA = [&](int kt, int s) {
            const float* src = (kt < 8) ? v0 : v1;
            int k0 = (kt & 7) * 32;
            #pragma unroll
            for (int i = 0; i < 2; ++i) {
                float4 f0 = {0,0,0,0}, f1 = {0,0,0,0};
                if (rowBase + rowA[i] < N) {
                    const float* p = src + (size_t)rowBase * 256 + offAg[i] + k0;
                    f0 = *(const float4*)p;
                    f1 = *(const float4*)(p + 4);
                }
                rA[s][i * 2]     = f0;
                rA[s][i * 2 + 1] = f1;
            }
        };
        auto writeA = [&](int s, int buf) {
            #pragma unroll
            for (int i = 0; i < 2; ++i)
                *(bf16x8*)&As[buf][offAw[i]] = pack8(rA[s][i * 2], rA[s][i * 2 + 1]);
        };
        auto stageBglds = [&](int kt, int buf) {
            int k0 = kt * 32;
            #pragma unroll
            for (int j = 0; j < 2; ++j)
                GLDS16(Wb + offBgl[j] + k0, &Bs[buf][(wid + j * 4) * 512]);
        };
        auto loadB = [&](int kt, int s) {   // fallback: W f32
            int k0 = kt * 32;
            #pragma unroll
            for (int i = 0; i < 2; ++i) {
                const float* p = Wf + offBg[i] + k0;
                rB[s][i * 2]     = *(const float4*)p;
                rB[s][i * 2 + 1] = *(const float4*)(p + 4);
            }
        };
        auto writeB = [&](int s, int buf) {
            #pragma unroll
            for (int i = 0; i < 2; ++i)
                *(bf16x8*)&Bs[buf][offBw[i]] = pack8(rB[s][i * 2], rB[s][i * 2 + 1]);
        };

        // ---- prologue ----
        if constexpr (WBF16) stageBglds(0, 0); else loadB(0, 0);
        loadA(0, 0);
        loadA(1, 1);
        if constexpr (!WBF16) loadB(1, 1);
        writeA(0, 0);
        if constexpr (!WBF16) writeB(0, 0);

        // ---- K loop: 1 barrier/step; loads for kt+2 issued right after it ----
        #pragma unroll
        for (int kt = 0; kt < NK; ++kt) {
            int cur = kt & 1;
            __syncthreads();                 // As/Bs[cur] staged & visible
            if constexpr (WBF16) {
                if (kt + 1 < NK) stageBglds(kt + 1, cur ^ 1);
            }
            if (kt + 2 < NK) {
                loadA(kt + 2, cur);          // full body of flight before next drain
                if constexpr (!WBF16) loadB(kt + 2, cur);
            }
            bf16x8 af[4], bf[4];
            #pragma unroll
            for (int f = 0; f < 4; ++f) af[f] = *(const bf16x8*)&As[cur][offAf[f]];
            #pragma unroll
            for (int f = 0; f < 4; ++f) bf[f] = *(const bf16x8*)&Bs[cur][offBf[f]];
            #pragma unroll
            for (int mf = 0; mf < 4; ++mf)
                #pragma unroll
                for (int nf = 0; nf < 4; ++nf)
                    acc[mf][nf] = __builtin_amdgcn_mfma_f32_16x16x32_bf16(
                        af[mf], bf[nf], acc[mf][nf], 0, 0, 0);
            if (kt + 1 < NK) {
                writeA(cur ^ 1, cur ^ 1);    // counted vmcnt on kt+1 A loads
                if constexpr (!WBF16) writeB(cur ^ 1, cur ^ 1);
            }
        }

        // ---- epilogue: bias + relu + row-mask -> per-lane column partials ----
        #pragma unroll
        for (int nf = 0; nf < 4; ++nf) {
            float bb = bv[nf];
            #pragma unroll
            for (int mf = 0; mf < 4; ++mf) {
                int rbase = rowBase + wr * 64 + mf * 16 + l4 * 4;
                #pragma unroll
                for (int r = 0; r < 4; ++r) {
                    float v = fmaxf(acc[mf][nf][r] + bb, 0.f);
                    if (rbase + r < N) csum[nf] += v;
                }
            }
        }
    }

    // ---- cross-lane column reduce ----
    #pragma unroll
    for (int nf = 0; nf < 4; ++nf) {
        float s = csum[nf];
        s += __shfl_xor(s, 16);
        s += __shfl_xor(s, 32);
        if (lane < 16) ldsPart[wid][nf * 16 + lane] = s;
    }
    __syncthreads();
    if (tid < 128) {
        int half = tid >> 6, c = tid & 63;
        float v = ldsPart[half][c] + ldsPart[half + 2][c];
        partial[(size_t)slot * 512 + cb * 128 + tid] = v;
    }
}

__global__ void reduce_partials(const float* __restrict__ partial, float* __restrict__ out)
{
    int c = blockIdx.x * blockDim.x + threadIdx.x;
    if (c < 512) {
        float s = 0.f;
        for (int s2 = 0; s2 < SLOTS; ++s2) s += partial[(size_t)s2 * 512 + c];
        out[c] = s;
    }
}

extern "C" void kernel_launch(void* const* d_in, const int* in_sizes, int n_in,
                              void* d_out, int out_size, void* d_ws, size_t ws_size,
                              hipStream_t stream)
{
    const float* v0 = (const float*)d_in[0];
    const float* v1 = (const float*)d_in[1];
    const float* Wf = (const float*)d_in[2];
    const float* b  = (const float*)d_in[3];
    float* out      = (float*)d_out;

    int N = in_sizes[0] / 256;
    int numRB = (N + BM - 1) / BM;

    size_t wbytes = (size_t)512 * 512 * sizeof(unsigned short);   // 512 KB
    size_t pbytes = (size_t)SLOTS * 512 * sizeof(float);          // 256 KB

    if (ws_size >= wbytes + pbytes) {
        unsigned short* Wb = (unsigned short*)d_ws;
        float* partial = (float*)((char*)d_ws + wbytes);
        conv_w_bf16<<<dim3(256), dim3(256), 0, stream>>>(Wf, Wb);
        fused_gemm_pool<true><<<dim3(SLOTS * NCB), dim3(256), 0, stream>>>(
            v0, v1, Wf, Wb, b, partial, N, numRB);
        reduce_partials<<<dim3(2), dim3(256), 0, stream>>>(partial, out);
    } else {
        float* partial = (float*)d_ws;                            // proven >= 256 KB
        fused_gemm_pool<false><<<dim3(SLOTS * NCB), dim3(256), 0, stream>>>(
            v0, v1, Wf, nullptr, b, partial, N, numRB);
        reduce_partials<<<dim3(2), dim3(256), 0, stream>>>(partial, out);
    }
}